// Round 1
// baseline (19.620 us; speedup 1.0000x reference)
//
#include <hip/hip_runtime.h>
#include <hip/hip_bf16.h>

constexpr int HS = 4;   // hedge slots
constexpr int NS = 64;  // neighbor samples == wavefront size
constexpr int T  = 32;  // n_types == output dim
constexpr int E  = 64;  // node embedding width

// One wave (64 lanes) per batch row.
__global__ __launch_bounds__(64)
void polyhype_kernel(const int*   __restrict__ neighbors,      // [B, HS]
                     const int*   __restrict__ train_hedges,   // [B]
                     const int*   __restrict__ labels,         // [B]
                     const int*   __restrict__ neighborhedges, // [N_NODES, NS]
                     const int*   __restrict__ hedgetypes,     // [N_HEDGES]
                     const int*   __restrict__ nodeEmb,        // [N_NODES, E]
                     const float* __restrict__ tf,             // [T, T]
                     const float* __restrict__ W1,             // [T, T]
                     const float* __restrict__ b1,             // [T]
                     const float* __restrict__ W2,             // [E, T]
                     const float* __restrict__ b2,             // [T]
                     float*       __restrict__ out,            // scores|sig|emb
                     int B)
{
    const int b    = blockIdx.x;
    const int lane = threadIdx.x;   // 0..63

    __shared__ float hist[HS][T];   // masked type histogram per hedge slot
    __shared__ float embacc[E];     // mean node embedding
    __shared__ float aggL[T];       // agg vector staging

    // zero the 128 histogram entries (2 per lane)
    ((float*)hist)[lane]      = 0.f;
    ((float*)hist)[lane + 64] = 0.f;
    __syncthreads();

    const int th = train_hedges[b];

    float den[HS];
    float eacc = 0.f;
    #pragma unroll
    for (int h = 0; h < HS; ++h) {
        const int node = neighbors[b * HS + h];              // scalar broadcast
        const int edge = neighborhedges[node * NS + lane];   // coalesced 256B row
        const bool m   = (edge != th);
        const int  ty  = hedgetypes[edge];                   // random 4B gather (L2/L3)
        den[h] = fmaxf((float)__popcll(__ballot(m)), 1.0f);  // uniform across wave
        if (m) atomicAdd(&hist[h][ty], 1.0f);
        eacc += (float)nodeEmb[node * E + lane];             // coalesced 256B row
    }
    embacc[lane] = eacc * (1.0f / HS);
    __syncthreads();

    const int t = lane & 31;
    float result;

    // lanes 0..31: aggregate types -> agg vector
    if (lane < T) {
        float agg = 0.f;
        #pragma unroll
        for (int h = 0; h < HS; ++h) {
            float s = 0.f;
            #pragma unroll 8
            for (int ty = 0; ty < T; ++ty)
                s += hist[h][ty] * tf[ty * T + t];           // coalesced tf row reads
            agg += s / den[h];
        }
        agg = agg * (1.0f / HS) + tf[labels[b] * T + t];     // + self vector
        aggL[t] = agg;
    }
    __syncthreads();

    if (lane < T) {
        // vector1 = agg @ W1 + b1
        float v = b1[t];
        #pragma unroll 8
        for (int u = 0; u < T; ++u)
            v += aggL[u] * W1[u * T + t];
        result = v;
    } else {
        // node_feat = mean(node_emb) @ W2 + b2
        float v = b2[t];
        #pragma unroll 8
        for (int e = 0; e < E; ++e)
            v += embacc[e] * W2[e * T + t];
        result = v;
    }

    // outputs: scores [B*T] | sigmoid(scores) [B*T] | embedding [B*2T]
    float* scores = out;
    float* sig    = out + (size_t)B * T;
    float* emb    = out + (size_t)2 * B * T;
    if (lane < T) {
        const float s = result;
        scores[b * T + t] = s;
        sig[b * T + t]    = 1.0f / (1.0f + expf(-s));
        emb[(size_t)b * 2 * T + t] = s;
    } else {
        emb[(size_t)b * 2 * T + T + t] = result;
    }
}

extern "C" void kernel_launch(void* const* d_in, const int* in_sizes, int n_in,
                              void* d_out, int out_size, void* d_ws, size_t ws_size,
                              hipStream_t stream) {
    const int*   neighbors      = (const int*)  d_in[0];
    const int*   train_hedges   = (const int*)  d_in[1];
    const int*   labels         = (const int*)  d_in[2];
    const int*   neighborhedges = (const int*)  d_in[3];
    const int*   hedgetypes     = (const int*)  d_in[4];
    const int*   nodeEmb        = (const int*)  d_in[5];
    const float* tf             = (const float*)d_in[6];
    const float* W1             = (const float*)d_in[7];
    const float* b1             = (const float*)d_in[8];
    const float* W2             = (const float*)d_in[9];
    const float* b2             = (const float*)d_in[10];
    float*       out            = (float*)      d_out;

    const int B = in_sizes[1];   // train_hedges is [B]

    polyhype_kernel<<<B, 64, 0, stream>>>(
        neighbors, train_hedges, labels, neighborhedges, hedgetypes, nodeEmb,
        tf, W1, b1, W2, b2, out, B);
}